// Round 1
// 162.278 us; speedup vs baseline: 1.2073x; 1.2073x over previous
//
#include <hip/hip_runtime.h>

typedef __bf16 bf16x8 __attribute__((ext_vector_type(8)));
typedef __bf16 bf16x4 __attribute__((ext_vector_type(4)));
typedef float f32x4 __attribute__((ext_vector_type(4)));
typedef float f32x16 __attribute__((ext_vector_type(16)));

__device__ __forceinline__ f32x4 mfma16(bf16x8 a, bf16x8 b, f32x4 c) {
  return __builtin_amdgcn_mfma_f32_16x16x32_bf16(a, b, c, 0, 0, 0);
}
__device__ __forceinline__ f32x16 mfma32(bf16x8 a, bf16x8 b, f32x16 c) {
  return __builtin_amdgcn_mfma_f32_32x32x16_bf16(a, b, c, 0, 0, 0);
}

// ---------------------------------------------------------------------------
// K0: convert Wf(32x256) | Wg(32x256) | Wh(256x256) fp32 -> Wb bf16 [320][256]
// ---------------------------------------------------------------------------
__global__ void wcvt_kernel(const float* __restrict__ Wf, const float* __restrict__ Wg,
                            const float* __restrict__ Wh, __bf16* __restrict__ Wb) {
  int i = blockIdx.x * 256 + threadIdx.x;  // 0..81919
  float v;
  if (i < 8192)       v = Wf[i];
  else if (i < 16384) v = Wg[i - 8192];
  else                v = Wh[i - 16384];
  Wb[i] = (__bf16)v;
}

// ---------------------------------------------------------------------------
// K1: projections. Grid 512 = b(4) x ntile(128 of 32 rows). 512 thr = 8 waves
//   O^T[n][o] = sum_c x[c][n] * Wb[o][c] + bias[o],  o in 0..319
// NEW: outputs are MFMA-fragment-packed so attn's B-operand loads coalesce:
//   o<64  -> QK_pk[b][nt(128)][qk(2)][frag(2)][h(2)][r(32)][e(8)] bf16
//            (element = proj feature o = qk*32 + frag*16 + h*8 + e at n=nt*32+r)
//   o>=64 -> V_pk[b][jc(256)][h(2)][c(256)][e(8)] bf16
//            (element = h[c][j] with j = jc*16 + h*8 + e), via LDS transpose
// ---------------------------------------------------------------------------
__global__ __launch_bounds__(512) void proj_kernel(
    const float* __restrict__ x, const float* __restrict__ bfv,
    const float* __restrict__ bgv, const float* __restrict__ bhv,
    const __bf16* __restrict__ Wb, __bf16* __restrict__ qkpk,
    __bf16* __restrict__ vpk) {
  __shared__ __align__(16) char smem[2560 + 18432];
  __bf16* xT = (__bf16*)smem;           // [32 n][40 c] bf16
  __bf16* ho = (__bf16*)(smem + 2560);  // [256 c][36 n] bf16

  const int t = threadIdx.x;
  const int l = t & 63, wg = t >> 6, q = l >> 4, l15 = l & 15;
  const int nh = wg & 1, oh = wg >> 1;   // oh 0..3
  const int bi = blockIdx.x;
  const int b = bi >> 7;
  const int nt = bi & 127;               // 32-row n tile
  const int n0 = nt << 5;

  const float* xb = x + (size_t)b * 256 * 4096;

  f32x4 acc[5];
#pragma unroll
  for (int i = 0; i < 5; i++) acc[i] = (f32x4){0.f, 0.f, 0.f, 0.f};

  const int c_rel = t >> 4;        // 0..31
  const int n2 = (t & 15) * 2;     // 0..30

#pragma unroll 1
  for (int kc = 0; kc < 8; kc++) {
    __syncthreads();
    float2 v = *(const float2*)(xb + (size_t)(kc * 32 + c_rel) * 4096 + n0 + n2);
    xT[(n2 + 0) * 40 + c_rel] = (__bf16)v.x;
    xT[(n2 + 1) * 40 + c_rel] = (__bf16)v.y;
    __syncthreads();
    bf16x8 af = *(const bf16x8*)(xT + (nh * 16 + l15) * 40 + q * 8);
    const __bf16* wp = Wb + (size_t)(oh * 80 + l15) * 256 + kc * 32 + q * 8;
#pragma unroll
    for (int ot = 0; ot < 5; ot++) {
      bf16x8 bfr = *(const bf16x8*)(wp + (size_t)ot * 16 * 256);
      acc[ot] = mfma16(af, bfr, acc[ot]);
    }
  }

#pragma unroll
  for (int ot = 0; ot < 5; ot++) {
    int o = oh * 80 + ot * 16 + l15;
    float bias = (o < 32) ? bfv[o] : (o < 64) ? bgv[o - 32] : bhv[o - 64];
    if (oh == 0 && ot < 4) {
      // QK path: o = ot*16 + l15 in 0..63 (wave-uniform branch)
      int qk = o >> 5, fr = (o >> 4) & 1, hh = (o >> 3) & 1, e = o & 7;
      size_t base = ((size_t)b * 128 + nt) * 2048 + qk * 1024 + fr * 512 + hh * 256;
#pragma unroll
      for (int r = 0; r < 4; r++) {
        int n_rel = nh * 16 + q * 4 + r;
        qkpk[base + n_rel * 8 + e] = (__bf16)(acc[ot][r] + bias);
      }
    } else {
#pragma unroll
      for (int r = 0; r < 4; r++) {
        int n_rel = nh * 16 + q * 4 + r;
        ho[(o - 64) * 36 + n_rel] = (__bf16)(acc[ot][r] + bias);
      }
    }
  }
  __syncthreads();
  // ho [256c][36n] -> V_pk (u32 = 2 consecutive e, always within one 8-run)
  unsigned short* vpku = (unsigned short*)vpk + (size_t)b * 1048576;
  const unsigned short* hou = (const unsigned short*)ho;
  for (int e = t; e < 4096; e += 512) {
    int c = e >> 4, nn = (e & 15) * 2;
    int n = n0 + nn;
    int jc = n >> 4, hh = (n >> 3) & 1, ee = n & 7;
    unsigned int vv = *(const unsigned int*)(hou + c * 36 + nn);
    *(unsigned int*)(vpku + (((size_t)(jc * 2 + hh) * 256 + c) * 8 + ee)) = vv;
  }
}

// ---------------------------------------------------------------------------
// K2: fused attention, split-j x4, register-prefetch software pipeline.
// Grid 1024 = 16 (b,jp) combos x 64 i-tiles(64 rows), XCD-pinned. 256 thr =
// 4 waves, 3 blocks/CU. Same pipeline as before (one barrier per 64-j step,
// P through LDS dbuf, V/K/Q prefetched in registers across the barrier).
// NEW: all Q/K/V fragment loads read the fragment-packed layouts ->
// fully coalesced (contiguous 512B per half-wave) instead of 64-line scatter.
// ---------------------------------------------------------------------------
__global__ __launch_bounds__(256, 3) void attn_kernel(
    const __bf16* __restrict__ qkpk, const __bf16* __restrict__ vpk,
    __bf16* __restrict__ pO, float* __restrict__ Lp) {
  __shared__ __align__(16) char smem[35072];
  // [0,17408) P buf0 [64][136]; [17408,34816) P buf1
  // epilogue: stage bf16 [256][66] = 33792 overlays P bufs
  // [34816,35072): Lbuf fp32 [64]
  __bf16* pb0 = (__bf16*)smem;
  __bf16* pb1 = (__bf16*)(smem + 17408);
  __bf16* stage = (__bf16*)smem;
  float* Lbuf = (float*)(smem + 34816);

  const int t = threadIdx.x;
  const int l = t & 63, w = t >> 6;          // 4 waves
  const int h = l >> 5, l31 = l & 31;

  const int bi = blockIdx.x;
  const int xcd = bi & 7, slot = bi >> 3;    // slot 0..127
  const int combo = xcd * 2 + (slot & 1);    // (b,jp) pinned to one XCD
  const int b = combo >> 2, jp = combo & 3;
  const int n0 = (slot >> 1) << 6;           // i-tile base, 64 rows

  const __bf16* qkb = qkpk + (size_t)b * 262144;
  const __bf16* vpb = vpk + (size_t)b * 1048576;
  const int jq0 = jp << 10;

  if (t < 64) Lbuf[t] = 0.f;

  const int it_s = w >> 1, jt = w & 1;       // producer tile ids

  // Q fragments, hoisted (loop-invariant). frag stride = 512 elems.
  const __bf16* qp = qkb + ((n0 >> 5) + it_s) * 2048 + h * 256 + l31 * 8;
  const bf16x8 qf0 = *(const bf16x8*)(qp);
  const bf16x8 qf1 = *(const bf16x8*)(qp + 512);

  f32x16 acc[2][2] = {};                     // [ci][ii] -> AGPRs
  float rs[16];
#pragma unroll
  for (int r = 0; r < 16; r++) rs[r] = 0.f;

  // V packed offset for this lane: [jc][h][c][e]; ci adds 32 c rows = 256 elems
  const int vco = h * 2048 + (w * 64 + l31) * 8;

  // ---- preloop: produce(0) into pb0, prefetch V(0) ----
  {
    const __bf16* kp = qkb + ((jq0 >> 5) + jt) * 2048 + 1024 + h * 256 + l31 * 8;
    bf16x8 kf0 = *(const bf16x8*)(kp);
    bf16x8 kf1 = *(const bf16x8*)(kp + 512);
    f32x16 s = {};
    s = mfma32(qf0, kf0, s);
    s = mfma32(qf1, kf1, s);
#pragma unroll
    for (int r = 0; r < 16; r++) {
      float p = __expf(s[r]);
      rs[r] += p;
      int i_loc = it_s * 32 + (r & 3) + 8 * (r >> 2) + 4 * h;
      pb0[i_loc * 136 + jt * 32 + l31] = (__bf16)p;
    }
  }
  bf16x8 vf[2][4];
#pragma unroll
  for (int ci = 0; ci < 2; ci++)
#pragma unroll
    for (int kc = 0; kc < 4; kc++)
      vf[ci][kc] = *(const bf16x8*)(vpb + (size_t)((jq0 >> 4) + kc) * 4096 + vco + ci * 256);
  __syncthreads();

  // ---- main loop: 16 steps of 64 j ----
#pragma unroll 1
  for (int it = 0; it < 16; ++it) {
    __bf16* buf = (it & 1) ? pb1 : pb0;
    __bf16* nb  = (it & 1) ? pb0 : pb1;
    const int jn4 = (jq0 >> 4) + (((it + 1) & 15) << 2);   // next step j/16 (wraps harmlessly)

    // K prefetch for produce(it+1) — issued first, consumed after consume
    bf16x8 kf0, kf1;
    if (it < 15) {
      const __bf16* kp = qkb + ((jn4 >> 1) + jt) * 2048 + 1024 + h * 256 + l31 * 8;
      kf0 = *(const bf16x8*)(kp);
      kf1 = *(const bf16x8*)(kp + 512);
    }

    // consume step it using prefetched vf; roll vf -> V(it+1) after each use
#pragma unroll
    for (int kc = 0; kc < 4; kc++) {
      bf16x8 pf0 = *(const bf16x8*)(buf + (size_t)(l31) * 136 + kc * 16 + h * 8);
      bf16x8 pf1 = *(const bf16x8*)(buf + (size_t)(32 + l31) * 136 + kc * 16 + h * 8);
      acc[0][0] = mfma32(pf0, vf[0][kc], acc[0][0]);
      acc[0][1] = mfma32(pf1, vf[0][kc], acc[0][1]);
      acc[1][0] = mfma32(pf0, vf[1][kc], acc[1][0]);
      acc[1][1] = mfma32(pf1, vf[1][kc], acc[1][1]);
      vf[0][kc] = *(const bf16x8*)(vpb + (size_t)(jn4 + kc) * 4096 + vco);
      vf[1][kc] = *(const bf16x8*)(vpb + (size_t)(jn4 + kc) * 4096 + vco + 256);
    }

    // produce step it+1 into the other buffer
    if (it < 15) {
      f32x16 s = {};
      s = mfma32(qf0, kf0, s);
      s = mfma32(qf1, kf1, s);
#pragma unroll
      for (int r = 0; r < 16; r++) {
        float p = __expf(s[r]);
        rs[r] += p;
        int i_loc = it_s * 32 + (r & 3) + 8 * (r >> 2) + 4 * h;
        nb[i_loc * 136 + jt * 32 + l31] = (__bf16)p;
      }
    }
    __syncthreads();
  }

  // rowsums (rows i = it_s*32 + pat; jt pair shares rows -> atomicAdd)
#pragma unroll
  for (int r = 0; r < 16; r++) {
    float s = rs[r];
    s += __shfl_xor(s, 1, 32); s += __shfl_xor(s, 2, 32);
    s += __shfl_xor(s, 4, 32); s += __shfl_xor(s, 8, 32);
    s += __shfl_xor(s, 16, 32);
    if (l31 == 0) {
      int row = it_s * 32 + (r & 3) + 8 * (r >> 2) + 4 * h;
      atomicAdd(&Lbuf[row], s);
    }
  }

  // epilogue: O^T tile -> LDS stage [256c][66i] (lane->c, reg-pattern->i)
#pragma unroll
  for (int ci = 0; ci < 2; ci++) {
    int c_loc = w * 64 + ci * 32 + l31;
#pragma unroll
    for (int ii = 0; ii < 2; ii++)
#pragma unroll
      for (int r = 0; r < 16; r++) {
        int i_loc = ii * 32 + (r & 3) + 8 * (r >> 2) + 4 * h;
        stage[(size_t)c_loc * 66 + i_loc] = (__bf16)acc[ci][ii][r];
      }
  }
  __syncthreads();

  // stage -> pO (coalesced u32), Lbuf -> Lp
  unsigned short* ob = (unsigned short*)pO + (size_t)(jp * 4 + b) * 256 * 4096 + n0;
  const unsigned short* su = (const unsigned short*)stage;
#pragma unroll 1
  for (int e = t; e < 8192; e += 256) {
    int c = e >> 5, i2 = (e & 31) * 2;
    unsigned int v = *(const unsigned int*)(su + c * 66 + i2);
    *(unsigned int*)(ob + (size_t)c * 4096 + i2) = v;
  }
  if (t < 64) Lp[(size_t)(jp * 4 + b) * 4096 + n0 + t] = Lbuf[t];
}

// ---------------------------------------------------------------------------
// K3: combine partials + normalize + residual.
//   out[b][c][i] = gamma * (sum_jp pO[jp][b][c][i]) / (sum_jp Lp[jp][b][i]) + x
// ---------------------------------------------------------------------------
__global__ __launch_bounds__(256) void norm_kernel(
    const float* __restrict__ x, const float* __restrict__ gamma_p,
    const __bf16* __restrict__ pO, const float* __restrict__ Lp,
    float* __restrict__ out) {
  const int bc = blockIdx.x;           // b = bc>>8, c = bc&255
  const int b = bc >> 8;
  const float gm = gamma_p[0];
  const float* xr = x + (size_t)bc * 4096;
  float* orow = out + (size_t)bc * 4096;
  const __bf16* pbase = pO + (size_t)bc * 4096;   // +jp*4194304
  const float* lbase = Lp + (size_t)b * 4096;     // +jp*16384

  for (int i0 = threadIdx.x * 4; i0 < 4096; i0 += 1024) {
    float4 xv = *(const float4*)(xr + i0);
    float s0 = 0.f, s1 = 0.f, s2 = 0.f, s3 = 0.f;
    float l0 = 0.f, l1 = 0.f, l2 = 0.f, l3 = 0.f;
#pragma unroll
    for (int jp = 0; jp < 4; jp++) {
      bf16x4 pv = *(const bf16x4*)(pbase + (size_t)jp * 4194304 + i0);
      s0 += (float)pv[0]; s1 += (float)pv[1]; s2 += (float)pv[2]; s3 += (float)pv[3];
      float4 lv = *(const float4*)(lbase + (size_t)jp * 16384 + i0);
      l0 += lv.x; l1 += lv.y; l2 += lv.z; l3 += lv.w;
    }
    float4 ov;
    ov.x = gm * s0 / l0 + xv.x;
    ov.y = gm * s1 / l1 + xv.y;
    ov.z = gm * s2 / l2 + xv.z;
    ov.w = gm * s3 / l3 + xv.w;
    *(float4*)(orow + i0) = ov;
  }
}

// ---------------------------------------------------------------------------
extern "C" void kernel_launch(void* const* d_in, const int* in_sizes, int n_in,
                              void* d_out, int out_size, void* d_ws, size_t ws_size,
                              hipStream_t stream) {
  const float* x   = (const float*)d_in[0];
  const float* Wf  = (const float*)d_in[1];
  const float* bfv = (const float*)d_in[2];
  const float* Wg  = (const float*)d_in[3];
  const float* bgv = (const float*)d_in[4];
  const float* Wh  = (const float*)d_in[5];
  const float* bhv = (const float*)d_in[6];
  const float* gm  = (const float*)d_in[7];
  float* out = (float*)d_out;

  char* ws = (char*)d_ws;
  __bf16* Wb   = (__bf16*)ws;                     //   160 KiB  @ 0
  __bf16* qkpk = (__bf16*)(ws + 262144);          //  2 MiB: [4][128][2][2][2][32][8]
  __bf16* vpk  = (__bf16*)(ws + 2359296);         //  8 MiB: [4][256][2][256][8]
  __bf16* pO   = (__bf16*)(ws + 10747904);        // 32 MiB: [4jp][4][256][4096] bf16
  float*  Lp   = (float*)(ws + 44302336);         // 256 KiB: [4jp][4][4096] fp32

  hipLaunchKernelGGL(wcvt_kernel, dim3(320), dim3(256), 0, stream, Wf, Wg, Wh, Wb);
  hipLaunchKernelGGL(proj_kernel, dim3(512), dim3(512), 0, stream,
                     x, bfv, bgv, bhv, Wb, qkpk, vpk);
  hipLaunchKernelGGL(attn_kernel, dim3(1024), dim3(256), 0, stream,
                     qkpk, vpk, pO, Lp);
  hipLaunchKernelGGL(norm_kernel, dim3(1024), dim3(256), 0, stream,
                     x, gm, pO, Lp, out);
}

// Round 2
// 161.869 us; speedup vs baseline: 1.2103x; 1.0025x over previous
//
#include <hip/hip_runtime.h>

typedef __bf16 bf16x8 __attribute__((ext_vector_type(8)));
typedef __bf16 bf16x4 __attribute__((ext_vector_type(4)));
typedef float f32x4 __attribute__((ext_vector_type(4)));
typedef float f32x16 __attribute__((ext_vector_type(16)));

__device__ __forceinline__ f32x4 mfma16(bf16x8 a, bf16x8 b, f32x4 c) {
  return __builtin_amdgcn_mfma_f32_16x16x32_bf16(a, b, c, 0, 0, 0);
}
__device__ __forceinline__ f32x16 mfma32(bf16x8 a, bf16x8 b, f32x16 c) {
  return __builtin_amdgcn_mfma_f32_32x32x16_bf16(a, b, c, 0, 0, 0);
}

// ---------------------------------------------------------------------------
// K0: convert Wf(32x256) | Wg(32x256) | Wh(256x256) fp32 -> Wb bf16 [320][256]
// ---------------------------------------------------------------------------
__global__ void wcvt_kernel(const float* __restrict__ Wf, const float* __restrict__ Wg,
                            const float* __restrict__ Wh, __bf16* __restrict__ Wb) {
  int i = blockIdx.x * 256 + threadIdx.x;  // 0..81919
  float v;
  if (i < 8192)       v = Wf[i];
  else if (i < 16384) v = Wg[i - 8192];
  else                v = Wh[i - 16384];
  Wb[i] = (__bf16)v;
}

// ---------------------------------------------------------------------------
// K1: projections. Grid 512 = b(4) x ntile(128 of 32 rows). 512 thr = 8 waves
//   O^T[n][o] = sum_c x[c][n] * Wb[o][c] + bias[o],  o in 0..319
// Outputs are MFMA-fragment-packed so attn's B-operand loads coalesce:
//   o<64  -> QK_pk[b][nt(128)][qk(2)][frag(2)][h(2)][r(32)][e(8)] bf16
//   o>=64 -> V_pk[b][jc(256)][h(2)][c(256)][e(8)] bf16 (via LDS transpose)
// ---------------------------------------------------------------------------
__global__ __launch_bounds__(512) void proj_kernel(
    const float* __restrict__ x, const float* __restrict__ bfv,
    const float* __restrict__ bgv, const float* __restrict__ bhv,
    const __bf16* __restrict__ Wb, __bf16* __restrict__ qkpk,
    __bf16* __restrict__ vpk) {
  __shared__ __align__(16) char smem[2560 + 18432];
  __bf16* xT = (__bf16*)smem;           // [32 n][40 c] bf16
  __bf16* ho = (__bf16*)(smem + 2560);  // [256 c][36 n] bf16

  const int t = threadIdx.x;
  const int l = t & 63, wg = t >> 6, q = l >> 4, l15 = l & 15;
  const int nh = wg & 1, oh = wg >> 1;   // oh 0..3
  const int bi = blockIdx.x;
  const int b = bi >> 7;
  const int nt = bi & 127;               // 32-row n tile
  const int n0 = nt << 5;

  const float* xb = x + (size_t)b * 256 * 4096;

  f32x4 acc[5];
#pragma unroll
  for (int i = 0; i < 5; i++) acc[i] = (f32x4){0.f, 0.f, 0.f, 0.f};

  const int c_rel = t >> 4;        // 0..31
  const int n2 = (t & 15) * 2;     // 0..30

#pragma unroll 1
  for (int kc = 0; kc < 8; kc++) {
    __syncthreads();
    float2 v = *(const float2*)(xb + (size_t)(kc * 32 + c_rel) * 4096 + n0 + n2);
    xT[(n2 + 0) * 40 + c_rel] = (__bf16)v.x;
    xT[(n2 + 1) * 40 + c_rel] = (__bf16)v.y;
    __syncthreads();
    bf16x8 af = *(const bf16x8*)(xT + (nh * 16 + l15) * 40 + q * 8);
    const __bf16* wp = Wb + (size_t)(oh * 80 + l15) * 256 + kc * 32 + q * 8;
#pragma unroll
    for (int ot = 0; ot < 5; ot++) {
      bf16x8 bfr = *(const bf16x8*)(wp + (size_t)ot * 16 * 256);
      acc[ot] = mfma16(af, bfr, acc[ot]);
    }
  }

#pragma unroll
  for (int ot = 0; ot < 5; ot++) {
    int o = oh * 80 + ot * 16 + l15;
    float bias = (o < 32) ? bfv[o] : (o < 64) ? bgv[o - 32] : bhv[o - 64];
    if (oh == 0 && ot < 4) {
      // QK path: o = ot*16 + l15 in 0..63 (wave-uniform branch)
      int qk = o >> 5, fr = (o >> 4) & 1, hh = (o >> 3) & 1, e = o & 7;
      size_t base = ((size_t)b * 128 + nt) * 2048 + qk * 1024 + fr * 512 + hh * 256;
#pragma unroll
      for (int r = 0; r < 4; r++) {
        int n_rel = nh * 16 + q * 4 + r;
        qkpk[base + n_rel * 8 + e] = (__bf16)(acc[ot][r] + bias);
      }
    } else {
#pragma unroll
      for (int r = 0; r < 4; r++) {
        int n_rel = nh * 16 + q * 4 + r;
        ho[(o - 64) * 36 + n_rel] = (__bf16)(acc[ot][r] + bias);
      }
    }
  }
  __syncthreads();
  // ho [256c][36n] -> V_pk (u32 = 2 consecutive e, always within one 8-run)
  unsigned short* vpku = (unsigned short*)vpk + (size_t)b * 1048576;
  const unsigned short* hou = (const unsigned short*)ho;
  for (int e = t; e < 4096; e += 512) {
    int c = e >> 4, nn = (e & 15) * 2;
    int n = n0 + nn;
    int jc = n >> 4, hh = (n >> 3) & 1, ee = n & 7;
    unsigned int vv = *(const unsigned int*)(hou + c * 36 + nn);
    *(unsigned int*)(vpku + (((size_t)(jc * 2 + hh) * 256 + c) * 8 + ee)) = vv;
  }
}

// ---------------------------------------------------------------------------
// K2: fused attention, split-j x4, register-prefetch software pipeline.
// Grid 1024 = 16 (b,jp) combos x 64 i-tiles(64 rows), XCD-pinned.
// NEW: 512 thr = 8 waves, 2 blocks/CU (4 waves/SIMD). Role thinning:
//   - waves 0..3 produce the 4 32x32 S tiles (as before): 2 QK mfma32, raw
//     exp, rowsum in regs, P -> LDS dbuf [64][136].
//   - ALL 8 waves consume: wave w owns 32 c rows (c = w*32 + l31), acc 2x
//     f32x16 (32 AGPR), vf[4] (16 VGPR) register-rolled V prefetch.
// Waves 4..7 carry zero exp work -> pure {ds_read, mfma, vmem} streams keep
// the MFMA pipe busy while producers run their exp chains. One barrier/step.
// ---------------------------------------------------------------------------
__global__ __launch_bounds__(512, 4) void attn_kernel(
    const __bf16* __restrict__ qkpk, const __bf16* __restrict__ vpk,
    __bf16* __restrict__ pO, float* __restrict__ Lp) {
  __shared__ __align__(16) char smem[35072];
  // [0,17408) P buf0 [64][136]; [17408,34816) P buf1
  // epilogue: stage bf16 [256][66] = 33792 overlays P bufs
  // [34816,35072): Lbuf fp32 [64]
  __bf16* pb0 = (__bf16*)smem;
  __bf16* pb1 = (__bf16*)(smem + 17408);
  __bf16* stage = (__bf16*)smem;
  float* Lbuf = (float*)(smem + 34816);

  const int t = threadIdx.x;
  const int l = t & 63, w = t >> 6;          // 8 waves
  const int h = l >> 5, l31 = l & 31;
  const bool prod = (w < 4);

  const int bi = blockIdx.x;
  const int xcd = bi & 7, slot = bi >> 3;    // slot 0..127
  const int combo = xcd * 2 + (slot & 1);    // (b,jp) pinned to one XCD
  const int b = combo >> 2, jp = combo & 3;
  const int n0 = (slot >> 1) << 6;           // i-tile base, 64 rows

  const __bf16* qkb = qkpk + (size_t)b * 262144;
  const __bf16* vpb = vpk + (size_t)b * 1048576;
  const int jq0 = jp << 10;

  if (t < 64) Lbuf[t] = 0.f;

  const int it_s = (w >> 1) & 1, jt = w & 1; // producer tile ids (w<4)

  // Q fragments, hoisted (loop-invariant). frag stride = 512 elems.
  bf16x8 qf0, qf1;
  if (prod) {
    const __bf16* qp = qkb + ((n0 >> 5) + it_s) * 2048 + h * 256 + l31 * 8;
    qf0 = *(const bf16x8*)(qp);
    qf1 = *(const bf16x8*)(qp + 512);
  }

  f32x16 acc[2] = {};                        // [ii] -> AGPRs (32)
  float rs[16];
#pragma unroll
  for (int r = 0; r < 16; r++) rs[r] = 0.f;

  // V packed offset for this lane: [jc][h][c][e]; wave owns c = w*32 + l31
  const int vco = h * 2048 + (w * 32 + l31) * 8;

  // ---- preloop: produce(0) into pb0, prefetch V(0) ----
  if (prod) {
    const __bf16* kp = qkb + ((jq0 >> 5) + jt) * 2048 + 1024 + h * 256 + l31 * 8;
    bf16x8 kf0 = *(const bf16x8*)(kp);
    bf16x8 kf1 = *(const bf16x8*)(kp + 512);
    f32x16 s = {};
    s = mfma32(qf0, kf0, s);
    s = mfma32(qf1, kf1, s);
#pragma unroll
    for (int r = 0; r < 16; r++) {
      float p = __expf(s[r]);
      rs[r] += p;
      int i_loc = it_s * 32 + (r & 3) + 8 * (r >> 2) + 4 * h;
      pb0[i_loc * 136 + jt * 32 + l31] = (__bf16)p;
    }
  }
  bf16x8 vf[4];
#pragma unroll
  for (int kc = 0; kc < 4; kc++)
    vf[kc] = *(const bf16x8*)(vpb + (size_t)((jq0 >> 4) + kc) * 4096 + vco);
  __syncthreads();

  // ---- main loop: 16 steps of 64 j ----
#pragma unroll 1
  for (int it = 0; it < 16; ++it) {
    __bf16* buf = (it & 1) ? pb1 : pb0;
    __bf16* nb  = (it & 1) ? pb0 : pb1;
    const int jn4 = (jq0 >> 4) + (((it + 1) & 15) << 2);   // next step j/16 (wraps harmlessly)

    // K prefetch for produce(it+1) — issued first, consumed after consume
    bf16x8 kf0, kf1;
    if (prod && it < 15) {
      const __bf16* kp = qkb + ((jn4 >> 1) + jt) * 2048 + 1024 + h * 256 + l31 * 8;
      kf0 = *(const bf16x8*)(kp);
      kf1 = *(const bf16x8*)(kp + 512);
    }

    // consume step it using prefetched vf; roll vf -> V(it+1) after each use
#pragma unroll
    for (int kc = 0; kc < 4; kc++) {
      bf16x8 pf0 = *(const bf16x8*)(buf + (size_t)(l31) * 136 + kc * 16 + h * 8);
      bf16x8 pf1 = *(const bf16x8*)(buf + (size_t)(32 + l31) * 136 + kc * 16 + h * 8);
      acc[0] = mfma32(pf0, vf[kc], acc[0]);
      acc[1] = mfma32(pf1, vf[kc], acc[1]);
      vf[kc] = *(const bf16x8*)(vpb + (size_t)(jn4 + kc) * 4096 + vco);
    }

    // produce step it+1 into the other buffer (waves 0..3 only)
    if (prod && it < 15) {
      f32x16 s = {};
      s = mfma32(qf0, kf0, s);
      s = mfma32(qf1, kf1, s);
#pragma unroll
      for (int r = 0; r < 16; r++) {
        float p = __expf(s[r]);
        rs[r] += p;
        int i_loc = it_s * 32 + (r & 3) + 8 * (r >> 2) + 4 * h;
        nb[i_loc * 136 + jt * 32 + l31] = (__bf16)p;
      }
    }
    __syncthreads();
  }

  // rowsums (producer waves; jt pair shares rows -> atomicAdd)
  if (prod) {
#pragma unroll
    for (int r = 0; r < 16; r++) {
      float s = rs[r];
      s += __shfl_xor(s, 1, 32); s += __shfl_xor(s, 2, 32);
      s += __shfl_xor(s, 4, 32); s += __shfl_xor(s, 8, 32);
      s += __shfl_xor(s, 16, 32);
      if (l31 == 0) {
        int row = it_s * 32 + (r & 3) + 8 * (r >> 2) + 4 * h;
        atomicAdd(&Lbuf[row], s);
      }
    }
  }

  // epilogue: O^T tile -> LDS stage [256c][66i] (wave owns 32 c rows)
  {
    int c_loc = w * 32 + l31;
#pragma unroll
    for (int ii = 0; ii < 2; ii++)
#pragma unroll
      for (int r = 0; r < 16; r++) {
        int i_loc = ii * 32 + (r & 3) + 8 * (r >> 2) + 4 * h;
        stage[(size_t)c_loc * 66 + i_loc] = (__bf16)acc[ii][r];
      }
  }
  __syncthreads();

  // stage -> pO (coalesced u32), Lbuf -> Lp
  unsigned short* ob = (unsigned short*)pO + (size_t)(jp * 4 + b) * 256 * 4096 + n0;
  const unsigned short* su = (const unsigned short*)stage;
#pragma unroll 1
  for (int e = t; e < 8192; e += 512) {
    int c = e >> 5, i2 = (e & 31) * 2;
    unsigned int v = *(const unsigned int*)(su + c * 66 + i2);
    *(unsigned int*)(ob + (size_t)c * 4096 + i2) = v;
  }
  if (t < 64) Lp[(size_t)(jp * 4 + b) * 4096 + n0 + t] = Lbuf[t];
}

// ---------------------------------------------------------------------------
// K3: combine partials + normalize + residual.
//   out[b][c][i] = gamma * (sum_jp pO[jp][b][c][i]) / (sum_jp Lp[jp][b][i]) + x
// ---------------------------------------------------------------------------
__global__ __launch_bounds__(256) void norm_kernel(
    const float* __restrict__ x, const float* __restrict__ gamma_p,
    const __bf16* __restrict__ pO, const float* __restrict__ Lp,
    float* __restrict__ out) {
  const int bc = blockIdx.x;           // b = bc>>8, c = bc&255
  const int b = bc >> 8;
  const float gm = gamma_p[0];
  const float* xr = x + (size_t)bc * 4096;
  float* orow = out + (size_t)bc * 4096;
  const __bf16* pbase = pO + (size_t)bc * 4096;   // +jp*4194304
  const float* lbase = Lp + (size_t)b * 4096;     // +jp*16384

  for (int i0 = threadIdx.x * 4; i0 < 4096; i0 += 1024) {
    float4 xv = *(const float4*)(xr + i0);
    float s0 = 0.f, s1 = 0.f, s2 = 0.f, s3 = 0.f;
    float l0 = 0.f, l1 = 0.f, l2 = 0.f, l3 = 0.f;
#pragma unroll
    for (int jp = 0; jp < 4; jp++) {
      bf16x4 pv = *(const bf16x4*)(pbase + (size_t)jp * 4194304 + i0);
      s0 += (float)pv[0]; s1 += (float)pv[1]; s2 += (float)pv[2]; s3 += (float)pv[3];
      float4 lv = *(const float4*)(lbase + (size_t)jp * 16384 + i0);
      l0 += lv.x; l1 += lv.y; l2 += lv.z; l3 += lv.w;
    }
    float4 ov;
    ov.x = gm * s0 / l0 + xv.x;
    ov.y = gm * s1 / l1 + xv.y;
    ov.z = gm * s2 / l2 + xv.z;
    ov.w = gm * s3 / l3 + xv.w;
    *(float4*)(orow + i0) = ov;
  }
}

// ---------------------------------------------------------------------------
extern "C" void kernel_launch(void* const* d_in, const int* in_sizes, int n_in,
                              void* d_out, int out_size, void* d_ws, size_t ws_size,
                              hipStream_t stream) {
  const float* x   = (const float*)d_in[0];
  const float* Wf  = (const float*)d_in[1];
  const float* bfv = (const float*)d_in[2];
  const float* Wg  = (const float*)d_in[3];
  const float* bgv = (const float*)d_in[4];
  const float* Wh  = (const float*)d_in[5];
  const float* bhv = (const float*)d_in[6];
  const float* gm  = (const float*)d_in[7];
  float* out = (float*)d_out;

  char* ws = (char*)d_ws;
  __bf16* Wb   = (__bf16*)ws;                     //   160 KiB  @ 0
  __bf16* qkpk = (__bf16*)(ws + 262144);          //  2 MiB: [4][128][2][2][2][32][8]
  __bf16* vpk  = (__bf16*)(ws + 2359296);         //  8 MiB: [4][256][2][256][8]
  __bf16* pO   = (__bf16*)(ws + 10747904);        // 32 MiB: [4jp][4][256][4096] bf16
  float*  Lp   = (float*)(ws + 44302336);         // 256 KiB: [4jp][4][4096] fp32

  hipLaunchKernelGGL(wcvt_kernel, dim3(320), dim3(256), 0, stream, Wf, Wg, Wh, Wb);
  hipLaunchKernelGGL(proj_kernel, dim3(512), dim3(512), 0, stream,
                     x, bfv, bgv, bhv, Wb, qkpk, vpk);
  hipLaunchKernelGGL(attn_kernel, dim3(1024), dim3(512), 0, stream,
                     qkpk, vpk, pO, Lp);
  hipLaunchKernelGGL(norm_kernel, dim3(1024), dim3(256), 0, stream,
                     x, gm, pO, Lp, out);
}